// Round 24
// baseline (160.579 us; speedup 1.0000x reference)
//
#include <hip/hip_runtime.h>

#define T 32
#define C 2048
#define NTOT 600
#define NCLASS 20
#define NSUP 5
#define PER 30
#define NQPC 25
#define NQ 500
#define NQROWS (NQ * T)      // 16000
#define NPROWS (NCLASS * T)  // 640
#define GAMMA 0.1f
#define INVG 10.0f
#define BIG 1e10f
#define NSELF (NQ + NCLASS)  // 520
#define GEMM_BLKS 625
#define SYRK_BLKS_PAD 136  // multiple of 8 so gemm swizzle sees o%8 unchanged
#define SAMP_STRIDE 8192   // half8 per staged query sample: 256 chunks x 32 rows
#define STAGE_BLKS_A 2000  // (500*32/16 row-tiles) x 2 col-halves
#define STAGE_BLKS_B 80    // (640/16) x 2
#define LDS_PITCH 33       // half8 per LDS row (32 chunks + 1 pad)

typedef __fp16 half8 __attribute__((ext_vector_type(8)));
typedef __fp16 half4 __attribute__((ext_vector_type(4)));
typedef float f32x4 __attribute__((ext_vector_type(4)));

// ---------------- parallel stable counting sort (1 block) ----------------
__global__ __launch_bounds__(640) void sort_kernel(const int* __restrict__ target,
                                                   int* __restrict__ order,
                                                   int* __restrict__ qsrc) {
    __shared__ int tgt[NTOT];
    __shared__ int offs[NCLASS];
    __shared__ int ordl[NTOT];
    int tid = threadIdx.x;
    if (tid < NTOT) tgt[tid] = target[tid];
    __syncthreads();
    if (tid < NCLASS) {
        int o = 0;
        for (int i = 0; i < NTOT; i++) o += (tgt[i] < tid) ? 1 : 0;
        offs[tid] = o;
    }
    __syncthreads();
    if (tid < NTOT) {
        int c = tgt[tid];
        int rank = 0;
        for (int k = 0; k < NTOT; k++) rank += (k < tid && tgt[k] == c) ? 1 : 0;
        ordl[offs[c] + rank] = tid;
    }
    __syncthreads();
    if (tid < NTOT) order[tid] = ordl[tid];
    if (tid < NQ) qsrc[tid] = ordl[(tid / NQPC) * PER + NSUP + (tid % NQPC)];
}

// ---------------- staging: gather + f16 round + LDS transpose + norm partials -----
__global__ __launch_bounds__(256) void stage_kernel(const float* __restrict__ inp,
                                                    const int* __restrict__ qsrc,
                                                    const int* __restrict__ order,
                                                    half8* __restrict__ Ah,
                                                    half8* __restrict__ Bh,
                                                    float* __restrict__ x2part,
                                                    float* __restrict__ y2part) {
    __shared__ half8 lds[4][16][LDS_PITCH];  // 33.8 KB
    int tid = threadIdx.x;
    int lane = tid & 63, w = tid >> 6;
    int bid = blockIdx.x;
    bool isA = bid < STAGE_BLKS_A;
    int b = isA ? bid : bid - STAGE_BLKS_A;
    int rowblk = b >> 1, half = b & 1;
    int row0 = rowblk * 16;
    int colbase = half * 1024 + w * 256;  // this wave's float-col window
    int pidx = half * 4 + w;              // partial slot 0..7
    if (isA) {
        int q = row0 >> 5, rowin0 = row0 & 31;  // 16-row tile within one query sample
        const float* sbase = inp + (size_t)qsrc[q] * (T * C) + (size_t)rowin0 * C +
                             colbase + lane * 4;
#pragma unroll
        for (int rr = 0; rr < 16; rr++) {
            float4 v = *(const float4*)(sbase + (size_t)rr * C);
            half4 hv = {(__fp16)v.x, (__fp16)v.y, (__fp16)v.z, (__fp16)v.w};
            ((half4*)&lds[w][rr][0])[lane] = hv;  // contiguous 512B per wave
            float fx = (float)hv[0], fy = (float)hv[1], fz = (float)hv[2], fw = (float)hv[3];
            float s = fx * fx + fy * fy + fz * fz + fw * fw;
#pragma unroll
            for (int d = 1; d < 64; d <<= 1) s += __shfl_xor(s, d);
            if (lane == 0) x2part[(size_t)(row0 + rr) * 8 + pidx] = s;
        }
        __syncthreads();
        int chunkbase = half * 128 + w * 32;
        half8* dst = Ah + (size_t)q * SAMP_STRIDE + rowin0;
#pragma unroll
        for (int c = 0; c < 8; c++) {
            int idx = c * 64 + lane;         // 0..511
            int ch = idx >> 4, row = idx & 15;
            dst[(size_t)(chunkbase + ch) * 32 + row] = lds[w][row][ch];
        }
    } else {
#pragma unroll
        for (int rr = 0; rr < 16; rr++) {
            int rg = row0 + rr;
            int cls = rg >> 5, trow = rg & 31;
            const float* base = inp + (size_t)trow * C + colbase + lane * 4;
            float4 a = *(const float4*)(base + (size_t)order[cls * PER + 0] * (T * C));
            float4 b4 = *(const float4*)(base + (size_t)order[cls * PER + 1] * (T * C));
            float4 c = *(const float4*)(base + (size_t)order[cls * PER + 2] * (T * C));
            float4 d = *(const float4*)(base + (size_t)order[cls * PER + 3] * (T * C));
            float4 e = *(const float4*)(base + (size_t)order[cls * PER + 4] * (T * C));
            float4 m;
            m.x = (a.x + b4.x + c.x + d.x + e.x) * 0.2f;
            m.y = (a.y + b4.y + c.y + d.y + e.y) * 0.2f;
            m.z = (a.z + b4.z + c.z + d.z + e.z) * 0.2f;
            m.w = (a.w + b4.w + c.w + d.w + e.w) * 0.2f;
            half4 hv = {(__fp16)m.x, (__fp16)m.y, (__fp16)m.z, (__fp16)m.w};
            ((half4*)&lds[w][rr][0])[lane] = hv;
            float fx = (float)hv[0], fy = (float)hv[1], fz = (float)hv[2], fw = (float)hv[3];
            float s = fx * fx + fy * fy + fz * fz + fw * fw;
#pragma unroll
            for (int dd = 1; dd < 64; dd <<= 1) s += __shfl_xor(s, dd);
            if (lane == 0) y2part[(size_t)rg * 8 + pidx] = s;
        }
        __syncthreads();
        int chunkbase = half * 128 + w * 32;
#pragma unroll
        for (int c = 0; c < 8; c++) {
            int idx = c * 64 + lane;
            int ch = idx >> 4, row = idx & 15;
            Bh[(size_t)(chunkbase + ch) * NPROWS + row0 + row] = lds[w][row][ch];
        }
    }
}

// ---------------- merged: SYRK + GEMM with FUSED cross soft-DTW epilogue ----------
__global__ __launch_bounds__(256) void gemm_syrk_kernel(const half8* __restrict__ Ah,
                                                        const half8* __restrict__ Bh,
                                                        const float* __restrict__ x2part,
                                                        const float* __restrict__ y2part,
                                                        float* __restrict__ dxy,
                                                        float* __restrict__ gxx,
                                                        float* __restrict__ gyy) {
    __shared__ float dmat[4][2][32][32];  // per-wave 2-matrix DTW tile, 32 KB
    int tid = threadIdx.x, lane = tid & 63, wid = tid >> 6;
    int o = blockIdx.x;
    int g = lane >> 4, r = lane & 15;
    if (o < SYRK_BLKS_PAD) {
        // ---- SYRK path: one wave per 32x32 Gram matrix (short blocks first) ----
        int ww = o * 4 + wid;
        if (ww >= NSELF) return;
        f32x4 acc[2][2];
        f32x4 zero = {0.f, 0.f, 0.f, 0.f};
        acc[0][0] = zero; acc[0][1] = zero; acc[1][0] = zero; acc[1][1] = zero;
        if (ww < NQ) {
            const half8* p = Ah + (size_t)ww * SAMP_STRIDE + g * 32 + r;
            float* outp = gxx + (size_t)ww * (T * T);
#pragma unroll 4
            for (int t = 0; t < C / 32; t++) {
                half8 h0 = p[0], h1 = p[16];
                p += 128;  // next 4 chunks
                acc[0][0] = __builtin_amdgcn_mfma_f32_16x16x32_f16(h0, h0, acc[0][0], 0, 0, 0);
                acc[0][1] = __builtin_amdgcn_mfma_f32_16x16x32_f16(h0, h1, acc[0][1], 0, 0, 0);
                acc[1][0] = __builtin_amdgcn_mfma_f32_16x16x32_f16(h1, h0, acc[1][0], 0, 0, 0);
                acc[1][1] = __builtin_amdgcn_mfma_f32_16x16x32_f16(h1, h1, acc[1][1], 0, 0, 0);
            }
#pragma unroll
            for (int mi = 0; mi < 2; mi++)
#pragma unroll
                for (int ni = 0; ni < 2; ni++)
#pragma unroll
                    for (int j = 0; j < 4; j++)
                        outp[(mi * 16 + g * 4 + j) * T + ni * 16 + r] = acc[mi][ni][j];
        } else {
            int row0 = (ww - NQ) * 32;
            float* outp = gyy + (size_t)(ww - NQ) * (T * T);
#pragma unroll 4
            for (int t = 0; t < C / 32; t++) {
                size_t base = (size_t)(t * 4 + g) * NPROWS + row0 + r;
                half8 h0 = Bh[base], h1 = Bh[base + 16];
                acc[0][0] = __builtin_amdgcn_mfma_f32_16x16x32_f16(h0, h0, acc[0][0], 0, 0, 0);
                acc[0][1] = __builtin_amdgcn_mfma_f32_16x16x32_f16(h0, h1, acc[0][1], 0, 0, 0);
                acc[1][0] = __builtin_amdgcn_mfma_f32_16x16x32_f16(h1, h0, acc[1][0], 0, 0, 0);
                acc[1][1] = __builtin_amdgcn_mfma_f32_16x16x32_f16(h1, h1, acc[1][1], 0, 0, 0);
            }
#pragma unroll
            for (int mi = 0; mi < 2; mi++)
#pragma unroll
                for (int ni = 0; ni < 2; ni++)
#pragma unroll
                    for (int j = 0; j < 4; j++)
                        outp[(mi * 16 + g * 4 + j) * T + ni * 16 + r] = acc[mi][ni][j];
        }
        return;
    }
    // ---- GEMM path: dots = Ah*Bh^T, 1 MFMA term, register-direct, deep unroll ----
    int oo = o - SYRK_BLKS_PAD;  // 0..624; SYRK_BLKS_PAD%8==0 keeps oo%8==o%8
    int xcd = oo & 7, slot = oo >> 3;
    int v = (xcd < 1 ? xcd * 79 : 79 + (xcd - 1) * 78) + slot;  // bijective over 625=8*78+1
    int bm = v / 5, bn = v % 5;
    int wr = wid >> 1, wc = wid & 1;
    int m0 = bm * 128 + wr * 64, n0 = bn * 128 + wc * 64;  // this wave's 64x64 tile
    int q0 = m0 >> 5;   // two query samples
    int p0 = n0 >> 5;   // two protos
    const half8* pA0 = Ah + (size_t)q0 * SAMP_STRIDE + g * 32 + r;
    const half8* pA1 = pA0 + SAMP_STRIDE;
    const half8* pB = Bh + (size_t)g * NPROWS + n0 + r;
    f32x4 acc[4][4];
    f32x4 zero = {0.f, 0.f, 0.f, 0.f};
#pragma unroll
    for (int mi = 0; mi < 4; mi++)
#pragma unroll
        for (int ni = 0; ni < 4; ni++) acc[mi][ni] = zero;
#pragma unroll 8
    for (int t = 0; t < C / 32; t++) {
        half8 ah[4], bh[4];
        ah[0] = pA0[0];
        ah[1] = pA0[16];
        ah[2] = pA1[0];
        ah[3] = pA1[16];
#pragma unroll
        for (int i = 0; i < 4; i++) bh[i] = pB[i * 16];
        pA0 += 128;
        pA1 += 128;
        pB += 4 * NPROWS;
#pragma unroll
        for (int mi = 0; mi < 4; mi++)
#pragma unroll
            for (int ni = 0; ni < 4; ni++)
                acc[mi][ni] = __builtin_amdgcn_mfma_f32_16x16x32_f16(ah[mi], bh[ni], acc[mi][ni], 0, 0, 0);
    }
    // ---- fused cross soft-DTW epilogue (scaled domain) ----
    int jj = lane & 31;
    int hh = lane >> 5;  // which query of the pair this 32-lane half handles
    float xreg, cj0, cj1;
    {
        const float* xp = x2part + ((size_t)(q0 + hh) * 32 + jj) * 8;
        const float* y0 = y2part + ((size_t)p0 * 32 + jj) * 8;
        const float* y1 = y2part + ((size_t)(p0 + 1) * 32 + jj) * 8;
        float sx = 0.f, s0 = 0.f, s1 = 0.f;
#pragma unroll
        for (int p = 0; p < 8; p++) {
            sx += xp[p];
            s0 += y0[p];
            s1 += y1[p];
        }
        xreg = sx;
        cj0 = s0;
        cj1 = s1;
    }
#pragma unroll
    for (int pp = 0; pp < 2; pp++) {
        __syncthreads();  // protect prior pass reads before overwriting dmat
#pragma unroll
        for (int qi = 0; qi < 2; qi++)
#pragma unroll
            for (int m2 = 0; m2 < 2; m2++)
#pragma unroll
                for (int nn = 0; nn < 2; nn++)
#pragma unroll
                    for (int j = 0; j < 4; j++)
                        dmat[wid][qi][m2 * 16 + g * 4 + j][nn * 16 + r] =
                            acc[qi * 2 + m2][pp * 2 + nn][j];
        __syncthreads();
        float cjv = pp ? cj1 : cj0;
        const float* cm = &dmat[wid][hh][0][0];
        float my_prev = BIG, my_prev2 = BIG;
        int ip = 0 - jj; ip = ip < 0 ? 0 : ip;
        float nxt = cm[ip * 32 + jj];
        for (int k = 0; k < 63; k++) {
            float cur = nxt;
            int in = k + 1 - jj; in = in < 0 ? 0 : (in > 31 ? 31 : in);
            nxt = cm[in * 32 + jj];  // bank = jj: conflict-free
            float lp = __shfl_up(my_prev, 1, 32);
            float dg = __shfl_up(my_prev2, 1, 32);
            if (jj == 0) { lp = BIG; dg = (k == 0) ? 0.f : BIG; }
            float up = my_prev;
            int i = k - jj;
            float ai = __shfl(xreg, i & 31, 32);
            float ds = (ai + cjv - 2.0f * cur) * INVG;  // off-critical-path scale
            float mn = fminf(dg, fminf(up, lp));
            float ssum = __expf(mn - dg) + __expf(mn - up) + __expf(mn - lp);
            float rv = ds + mn - __logf(ssum);
            bool act = (i >= 0) && (i < 32);
            my_prev2 = my_prev;
            my_prev = act ? rv : my_prev;
        }
        if (jj == 31) dxy[(size_t)(q0 + hh) * NCLASS + p0 + pp] = my_prev * GAMMA;
    }
}

// ---------------- wavefront soft-DTW for the 520 self matrices (scaled domain) ----
__global__ __launch_bounds__(256) void softdtw_self_kernel(
        const float* __restrict__ gxx, const float* __restrict__ gyy,
        float* __restrict__ dxx, float* __restrict__ dyy) {
    int tid = threadIdx.x;
    int jj = tid & 31;
    int mm = blockIdx.x * 8 + (tid >> 5);
    bool valid = mm < NSELF;
    int mmc = valid ? mm : 0;
    const float* base = (mmc < NQ) ? gxx + (size_t)mmc * (T * T)
                                   : gyy + (size_t)(mmc - NQ) * (T * T);
    float* outp = (mmc < NQ) ? dxx + mmc : dyy + (mmc - NQ);
    float cjv = base[jj * 33];  // diag (j,j)
    float xreg = cjv;
    float my_prev = BIG, my_prev2 = BIG;
    int ip = 0 - jj; ip = ip < 0 ? 0 : ip;
    float nxt = base[ip * T + jj];
    for (int k = 0; k < 63; k++) {
        float cur = nxt;
        int in = k + 1 - jj; in = in < 0 ? 0 : (in > 31 ? 31 : in);
        nxt = base[in * T + jj];
        float lp = __shfl_up(my_prev, 1, 32);
        float dg = __shfl_up(my_prev2, 1, 32);
        if (jj == 0) { lp = BIG; dg = (k == 0) ? 0.f : BIG; }
        float up = my_prev;
        int i = k - jj;
        float ai = __shfl(xreg, i & 31, 32);
        float ds = (ai + cjv - 2.0f * cur) * INVG;
        float mn = fminf(dg, fminf(up, lp));
        float ssum = __expf(mn - dg) + __expf(mn - up) + __expf(mn - lp);
        float rv = ds + mn - __logf(ssum);
        bool act = (i >= 0) && (i < 32);
        my_prev2 = my_prev;
        my_prev = act ? rv : my_prev;
    }
    if (jj == 31 && valid) *outp = my_prev * GAMMA;
}

// ---------------- finalize: dist, log-softmax, loss, acc ----------------
__global__ __launch_bounds__(512) void finalize_kernel(const float* __restrict__ dxy,
                                                       const float* __restrict__ dxx,
                                                       const float* __restrict__ dyy,
                                                       float* __restrict__ out) {
    __shared__ float sl[512];
    __shared__ float sa[512];
    int q = threadIdx.x;
    float bl = 0.f, fl = 0.f;
    if (q < NQ) {
        float dxxq = dxx[q];
        int cq = q / NQPC;
        float dd[NCLASS];
#pragma unroll
        for (int m = 0; m < NCLASS; m++)
            dd[m] = dxy[q * NCLASS + m] - 0.5f * (dxxq + dyy[m]);
        float best = dd[0];
        int bi = 0;
#pragma unroll
        for (int m = 1; m < NCLASS; m++) {
            if (dd[m] < best) { best = dd[m]; bi = m; }
        }
        float s = 0.f;
        float dcq = dd[0];
#pragma unroll
        for (int m = 0; m < NCLASS; m++) {
            s += __expf(best - dd[m]);
            if (m == cq) dcq = dd[m];
        }
        float lse = __logf(s) - best;
        bl = dcq + lse;
        out[2 + q] = bl;
        fl = (bi == cq) ? 1.f : 0.f;
    }
    sl[threadIdx.x] = bl;
    sa[threadIdx.x] = fl;
    __syncthreads();
    for (int off = 256; off; off >>= 1) {
        if (threadIdx.x < off) {
            sl[threadIdx.x] += sl[threadIdx.x + off];
            sa[threadIdx.x] += sa[threadIdx.x + off];
        }
        __syncthreads();
    }
    if (threadIdx.x == 0) {
        out[0] = sl[0] / (float)NQ;
        out[1] = sa[0] / (float)NQ;
    }
}

extern "C" void kernel_launch(void* const* d_in, const int* in_sizes, int n_in,
                              void* d_out, int out_size, void* d_ws, size_t ws_size,
                              hipStream_t stream) {
    const float* inp = (const float*)d_in[0];
    const int* target = (const int*)d_in[1];
    float* out = (float*)d_out;
    char* ws = (char*)d_ws;

    size_t off = 0;
    auto carve = [&](size_t bytes) {
        void* p = ws + off;
        off = (off + bytes + 255) & ~(size_t)255;
        return p;
    };
    int* order = (int*)carve(NTOT * sizeof(int));
    int* qsrc = (int*)carve(NQ * sizeof(int));
    float* x2part = (float*)carve((size_t)NQROWS * 8 * sizeof(float));  // 512 KB
    float* y2part = (float*)carve((size_t)NPROWS * 8 * sizeof(float));  // 20 KB
    float* gxx = (float*)carve((size_t)NQ * T * T * sizeof(float));
    float* gyy = (float*)carve((size_t)NCLASS * T * T * sizeof(float));
    float* dxy = (float*)carve((size_t)NQ * NCLASS * sizeof(float));
    float* dxx = (float*)carve((size_t)NQ * sizeof(float));
    float* dyy = (float*)carve((size_t)NCLASS * sizeof(float));
    half8* Ah = (half8*)carve((size_t)NQ * SAMP_STRIDE * 16);  // 65.5 MB per-query
    half8* Bh = (half8*)carve((size_t)(C / 8) * NPROWS * 16);  // 2.6 MB (L2-resident)
    (void)ws_size;

    sort_kernel<<<1, 640, 0, stream>>>(target, order, qsrc);
    stage_kernel<<<STAGE_BLKS_A + STAGE_BLKS_B, 256, 0, stream>>>(inp, qsrc, order, Ah, Bh,
                                                                  x2part, y2part);
    gemm_syrk_kernel<<<SYRK_BLKS_PAD + GEMM_BLKS, 256, 0, stream>>>(Ah, Bh, x2part, y2part,
                                                                    dxy, gxx, gyy);
    softdtw_self_kernel<<<(NSELF + 7) / 8, 256, 0, stream>>>(gxx, gyy, dxx, dyy);
    finalize_kernel<<<1, 512, 0, stream>>>(dxy, dxx, dyy, out);
}